// Round 1
// baseline (399.996 us; speedup 1.0000x reference)
//
#include <hip/hip_runtime.h>

typedef _Float16 f16;
typedef __attribute__((ext_vector_type(2)))  _Float16 f16x2;
typedef __attribute__((ext_vector_type(8)))  _Float16 f16x8;
typedef __attribute__((ext_vector_type(4)))  float    fvec4;
typedef __attribute__((ext_vector_type(4)))  float    f32x4;
typedef __attribute__((ext_vector_type(16))) float    f32x16;
typedef __attribute__((ext_vector_type(4)))  unsigned int uint4v;

#define NKEY  784
#define NKEYP 800
#define NQ    196
#define NQP   224

static __device__ __forceinline__ f32x4 mfma16(f16x8 a, f16x8 b, f32x4 c) {
    return __builtin_amdgcn_mfma_f32_16x16x32_f16(a, b, c, 0, 0, 0);
}
static __device__ __forceinline__ f32x16 mfma32(f16x8 a, f16x8 b, f32x16 c) {
    return __builtin_amdgcn_mfma_f32_32x32x16_f16(a, b, c, 0, 0, 0);
}
static __device__ __forceinline__ unsigned pk2(float a, float b) {
    f16x2 t; t[0] = (_Float16)a; t[1] = (_Float16)b;
    return __builtin_bit_cast(unsigned, t);
}
static __device__ __forceinline__ f32x16 z16() {
    f32x16 v;
#pragma unroll
    for (int i = 0; i < 16; ++i) v[i] = 0.f;
    return v;
}

// ---------------- prep: fold BN into scale/shift ----------------
__global__ void prep_scales(const float* __restrict__ g, const float* __restrict__ be,
                            const float* __restrict__ mu, const float* __restrict__ va,
                            float* __restrict__ s, float* __restrict__ t, int n) {
    int i = blockIdx.x * 256 + threadIdx.x;
    if (i < n) {
        float sv = g[i] * rsqrtf(va[i] + 1e-5f);
        s[i] = sv;
        t[i] = be[i] - mu[i] * sv;
    }
}

// ---------------- prep: gather bias transposed [h][key(800)][q(224)] ----------------
__global__ void prep_bias(const float* __restrict__ biases, const int* __restrict__ idxs,
                          float* __restrict__ biasT, int n_off) {
    int tid = blockIdx.x * 256 + threadIdx.x;            // exactly 8*800*224
    int h   = tid / (NKEYP * NQP);
    int rem = tid - h * (NKEYP * NQP);
    int key = rem / NQP;
    int q   = rem - key * NQP;
    float v = 0.f;
    if (key < NKEY && q < NQ) v = biases[h * n_off + idxs[q * NKEY + key]];
    biasT[tid] = v;
}

// ---------------- GEMM + BN epilogue ----------------
// MODE 0: kv  : A = hidden f32 [100352][256], W = w_kv  [640][256] -> kv  f16 [1024][800][80]
// MODE 1: q   : A = hidden f32 subsampled,    W = w_q   [128][256] -> q   f16 [1024][224][16]
// MODE 2: proj: A = attnout f16 [25088][512], W = w_proj[384][512] -> out f32 [25088][384]
template <int MODE>
__global__ __launch_bounds__(256) void gemm_bn(const void* __restrict__ Ap,
                                               const float* __restrict__ W,
                                               const float* __restrict__ sc,
                                               const float* __restrict__ sh,
                                               void* __restrict__ Out) {
    constexpr int K = (MODE == 2) ? 512 : 256;
    constexpr int KSTEPS = K / 32;
    __shared__ __align__(16) f16 As[64][40];   // stride 40 f16 = 80B -> bank-friendly, 16B aligned
    __shared__ __align__(16) f16 Bs[64][40];

    const int m0 = blockIdx.x * 64;
    const int n0 = blockIdx.y * 64;
    const int t = threadIdx.x;
    const int lane = t & 63;
    const int wid = t >> 6;
    const int wm = wid >> 1, wn = wid & 1;
    const int srow = t >> 2;
    const int scol = (t & 3) * 8;

    size_t arow;
    if constexpr (MODE == 1) {
        int m = m0 + srow;
        int b = m / 196, nn = m - b * 196;
        arow = (size_t)b * 784 + (nn / 14) * 56 + (nn % 14) * 2;
    } else {
        arow = (size_t)(m0 + srow);
    }
    const float* wrow = W + (size_t)(n0 + srow) * K + scol;

    f32x4 acc[2][2];
#pragma unroll
    for (int i = 0; i < 2; ++i)
#pragma unroll
        for (int j = 0; j < 2; ++j) acc[i][j] = (f32x4){0.f, 0.f, 0.f, 0.f};

    for (int kt = 0; kt < KSTEPS; ++kt) {
        const int k0 = kt * 32;
        if constexpr (MODE == 2) {
            const f16* a = (const f16*)Ap + arow * 512 + k0 + scol;
            *(f16x8*)&As[srow][scol] = *(const f16x8*)a;
        } else {
            const float* a = (const float*)Ap + arow * 256 + k0 + scol;
            fvec4 v0 = *(const fvec4*)a;
            fvec4 v1 = *(const fvec4*)(a + 4);
            f16x8 hv;
            hv[0] = (f16)v0[0]; hv[1] = (f16)v0[1]; hv[2] = (f16)v0[2]; hv[3] = (f16)v0[3];
            hv[4] = (f16)v1[0]; hv[5] = (f16)v1[1]; hv[6] = (f16)v1[2]; hv[7] = (f16)v1[3];
            *(f16x8*)&As[srow][scol] = hv;
        }
        {
            fvec4 v0 = *(const fvec4*)(wrow + k0);
            fvec4 v1 = *(const fvec4*)(wrow + k0 + 4);
            f16x8 hv;
            hv[0] = (f16)v0[0]; hv[1] = (f16)v0[1]; hv[2] = (f16)v0[2]; hv[3] = (f16)v0[3];
            hv[4] = (f16)v1[0]; hv[5] = (f16)v1[1]; hv[6] = (f16)v1[2]; hv[7] = (f16)v1[3];
            *(f16x8*)&Bs[srow][scol] = hv;
        }
        __syncthreads();
        const int fr = lane & 15;
        const int kq = (lane >> 4) * 8;
        f16x8 a0 = *(const f16x8*)&As[wm * 32 + fr][kq];
        f16x8 a1 = *(const f16x8*)&As[wm * 32 + 16 + fr][kq];
        f16x8 b0 = *(const f16x8*)&Bs[wn * 32 + fr][kq];
        f16x8 b1 = *(const f16x8*)&Bs[wn * 32 + 16 + fr][kq];
        acc[0][0] = mfma16(a0, b0, acc[0][0]);
        acc[0][1] = mfma16(a0, b1, acc[0][1]);
        acc[1][0] = mfma16(a1, b0, acc[1][0]);
        acc[1][1] = mfma16(a1, b1, acc[1][1]);
        __syncthreads();
    }

    const int fr = lane & 15;
    const int rg = (lane >> 4) * 4;
#pragma unroll
    for (int mt = 0; mt < 2; ++mt)
#pragma unroll
        for (int nt = 0; nt < 2; ++nt)
#pragma unroll
            for (int r = 0; r < 4; ++r) {
                int m = m0 + wm * 32 + mt * 16 + rg + r;
                int n = n0 + wn * 32 + nt * 16 + fr;
                float y = acc[mt][nt][r] * sc[n] + sh[n];
                if constexpr (MODE == 0) {
                    int b = m / 784, nn = m - b * 784;
                    int hd = n / 80, c = n - hd * 80;
                    ((f16*)Out)[((size_t)(b * 8 + hd) * NKEYP + nn) * 80 + c] = (f16)y;
                } else if constexpr (MODE == 1) {
                    int b = m / 196, nn = m - b * 196;
                    int hd = n >> 4, c = n & 15;
                    ((f16*)Out)[((size_t)(b * 8 + hd) * NQP + nn) * 16 + c] = (f16)y;
                } else {
                    ((float*)Out)[(size_t)m * 384 + n] = y;
                }
            }
}

// ---------------- fused attention ----------------
// 1 wave / block; block = (b, h, 32-q-row tile). Swapped QK^T: S^T = K(32x16) x Q^T(16x32).
// Lane owns q = lane&31 for softmax (keys split across lane halves, merged via shfl_xor 32).
__global__ __launch_bounds__(64) void attn_fused(const f16* __restrict__ kv,
                                                 const f16* __restrict__ qw,
                                                 const float* __restrict__ biasT,
                                                 f16* __restrict__ ao) {
    const int blk = blockIdx.x;
    const int qt = blk % 7;
    const int bh = blk / 7;
    const int b = bh >> 3, h = bh & 7;
    const int lane = threadIdx.x;
    const int l31 = lane & 31;
    const int hh = lane >> 5;
    const int q0 = qt * 32;

    const f16* kvb = kv + (size_t)bh * (NKEYP * 80);
    const f16x8 bq = *(const f16x8*)(qw + ((size_t)bh * NQP + q0 + l31) * 16 + hh * 8);
    const float* bb = biasT + (size_t)h * (NKEYP * NQP) + (q0 + l31);

    float mrun = -1e30f;
    float lsum = 0.f;
    f32x16 o0 = z16(), o1 = z16();

    for (int key0 = 0; key0 < NKEY; key0 += 32) {
        f16x8 ak = *(const f16x8*)(kvb + (size_t)(key0 + l31) * 80 + hh * 8);
        f32x16 s = mfma32(ak, bq, z16());
        const bool full = (key0 + 32) <= NKEY;
        float p[16];
        float cmax = -3.0e38f;
#pragma unroll
        for (int r = 0; r < 16; ++r) {
            const int cr = (r & 3) + ((r >> 2) << 3) + (hh << 2);
            const int key = key0 + cr;
            float sv = s[r] * 0.25f + bb[(size_t)key * NQP];
            if (!full && key >= NKEY) sv = -1e30f;
            p[r] = sv;
            cmax = fmaxf(cmax, sv);
        }
        cmax = fmaxf(cmax, __shfl_xor(cmax, 32));
        if (__any(cmax > mrun + 8.f)) {          // defer-max: rescale only when needed
            float mnew = fmaxf(mrun, cmax);
            float f = __expf(mrun - mnew);
            mrun = mnew;
            lsum *= f;
#pragma unroll
            for (int r = 0; r < 16; ++r) {
                const int cr = (r & 3) + ((r >> 2) << 3) + (hh << 2);
                float fr2 = __shfl(f, cr);
                o0[r] *= fr2;
                o1[r] *= fr2;
            }
        }
        float psum = 0.f;
#pragma unroll
        for (int r = 0; r < 16; ++r) {
            p[r] = __expf(p[r] - mrun);
            psum += p[r];
        }
        lsum += psum;
        // pack own 4-key groups: own[g] = keys 8g + 4*hh + 0..3 for q = l31
        unsigned g0l = pk2(p[0], p[1]),   g0h = pk2(p[2], p[3]);
        unsigned g1l = pk2(p[4], p[5]),   g1h = pk2(p[6], p[7]);
        unsigned g2l = pk2(p[8], p[9]),   g2h = pk2(p[10], p[11]);
        unsigned g3l = pk2(p[12], p[13]), g3h = pk2(p[14], p[15]);
#pragma unroll
        for (int sH = 0; sH < 2; ++sH) {
            unsigned self_lo = sH ? (hh ? g3l : g2l) : (hh ? g1l : g0l);
            unsigned self_hi = sH ? (hh ? g3h : g2h) : (hh ? g1h : g0h);
            unsigned tx_lo   = sH ? (hh ? g2l : g3l) : (hh ? g0l : g1l);
            unsigned tx_hi   = sH ? (hh ? g2h : g3h) : (hh ? g0h : g1h);
            unsigned rx_lo = __shfl_xor(tx_lo, 32);
            unsigned rx_hi = __shfl_xor(tx_hi, 32);
            uint4v w;
            w[0] = hh ? rx_lo : self_lo;
            w[1] = hh ? rx_hi : self_hi;
            w[2] = hh ? self_lo : rx_lo;
            w[3] = hh ? self_hi : rx_hi;
            f16x8 pa = __builtin_bit_cast(f16x8, w);
            // V fragment: B[kc][d], kc = hh*8+j -> key = key0+16*sH+8*hh+j ; d = l31 (+32)
            const f16* vb = kvb + (size_t)(key0 + sH * 16 + hh * 8) * 80 + 16 + l31;
            f16x8 bv0, bv1;
            if (full) {
#pragma unroll
                for (int j = 0; j < 8; ++j) {
                    bv0[j] = vb[(size_t)j * 80];
                    bv1[j] = vb[(size_t)j * 80 + 32];
                }
            } else {
#pragma unroll
                for (int j = 0; j < 8; ++j) {
                    const int key = key0 + sH * 16 + hh * 8 + j;
                    bool ok = key < NKEY;
                    bv0[j] = ok ? vb[(size_t)j * 80] : (f16)0.f;
                    bv1[j] = ok ? vb[(size_t)j * 80 + 32] : (f16)0.f;
                }
            }
            o0 = mfma32(pa, bv0, o0);
            o1 = mfma32(pa, bv1, o1);
        }
    }
    lsum += __shfl_xor(lsum, 32);
    const float inv = 1.0f / lsum;
#pragma unroll
    for (int r = 0; r < 16; ++r) {
        const int cr = (r & 3) + ((r >> 2) << 3) + (hh << 2);
        const float iq = __shfl(inv, cr);
        const int qg = q0 + cr;
        if (qg < NQ) {
            float v0 = o0[r] * iq, v1 = o1[r] * iq;
            float h0 = v0 * fminf(fmaxf(v0 + 3.f, 0.f), 6.f) * (1.f / 6.f);
            float h1 = v1 * fminf(fmaxf(v1 + 3.f, 0.f), 6.f) * (1.f / 6.f);
            f16* dst = ao + ((size_t)b * NQ + qg) * 512 + h * 64 + l31;
            dst[0] = (f16)h0;
            dst[32] = (f16)h1;
        }
    }
}

// ---------------- launch ----------------
extern "C" void kernel_launch(void* const* d_in, const int* in_sizes, int n_in,
                              void* d_out, int out_size, void* d_ws, size_t ws_size,
                              hipStream_t stream) {
    (void)n_in; (void)out_size; (void)ws_size;
    const float* hidden = (const float*)d_in[0];
    const float* w_kv   = (const float*)d_in[1];
    const float* kv_g   = (const float*)d_in[2];
    const float* kv_b   = (const float*)d_in[3];
    const float* kv_m   = (const float*)d_in[4];
    const float* kv_v   = (const float*)d_in[5];
    const float* w_q    = (const float*)d_in[6];
    const float* q_g    = (const float*)d_in[7];
    const float* q_b    = (const float*)d_in[8];
    const float* q_m    = (const float*)d_in[9];
    const float* q_v    = (const float*)d_in[10];
    const float* w_p    = (const float*)d_in[11];
    const float* p_g    = (const float*)d_in[12];
    const float* p_b    = (const float*)d_in[13];
    const float* p_m    = (const float*)d_in[14];
    const float* p_v    = (const float*)d_in[15];
    const float* biases = (const float*)d_in[16];
    const int*   idxs   = (const int*)d_in[17];
    const int n_off = in_sizes[16] / 8;

    char* ws = (char*)d_ws;
    const size_t SZ_KV = (size_t)1024 * NKEYP * 80 * 2;  // 131,072,000
    const size_t SZ_Q  = (size_t)1024 * NQP * 16 * 2;    //   7,340,032
    const size_t SZ_AO = (size_t)25088 * 512 * 2;        //  25,690,112
    const size_t SZ_BT = (size_t)8 * NKEYP * NQP * 4;    //   5,734,400
    f16*   kvbuf = (f16*)ws;
    f16*   qbuf  = (f16*)(ws + SZ_KV);
    f16*   aobuf = (f16*)(ws + SZ_KV + SZ_Q);
    float* btbuf = (float*)(ws + SZ_KV + SZ_Q + SZ_AO);
    float* scbuf = (float*)(ws + SZ_KV + SZ_Q + SZ_AO + SZ_BT);

    prep_scales<<<3, 256, 0, stream>>>(kv_g, kv_b, kv_m, kv_v, scbuf, scbuf + 640, 640);
    prep_scales<<<1, 256, 0, stream>>>(q_g, q_b, q_m, q_v, scbuf + 1280, scbuf + 1408, 128);
    prep_scales<<<2, 256, 0, stream>>>(p_g, p_b, p_m, p_v, scbuf + 1536, scbuf + 1920, 384);
    prep_bias<<<5600, 256, 0, stream>>>(biases, idxs, btbuf, n_off);
    gemm_bn<0><<<dim3(1568, 10), 256, 0, stream>>>(hidden, w_kv, scbuf, scbuf + 640, kvbuf);
    gemm_bn<1><<<dim3(392, 2), 256, 0, stream>>>(hidden, w_q, scbuf + 1280, scbuf + 1408, qbuf);
    attn_fused<<<7168, 64, 0, stream>>>(kvbuf, qbuf, btbuf, aobuf);
    gemm_bn<2><<<dim3(392, 6), 256, 0, stream>>>(aobuf, w_p, scbuf + 1536, scbuf + 1920, d_out);
}